// Round 1
// 436.077 us; speedup vs baseline: 1.1157x; 1.1157x over previous
//
#include <hip/hip_runtime.h>

// AbstractConv3D: 16 dense R^3 levels, 3x3x3 conv, C_in=C_out=16, B=2, fp32 I/O.
// Round 3: remove per-block weight-rebuild overhead + HW bf16 conversion.
//   - pack_weights (one-shot, 16 blocks): builds per-lane MFMA B-fragments
//     (bf16, lane layout = (quad,m) of the main kernel) into d_ws. Main kernel
//     loads them with 14 coalesced global_load_dwordx4 per lane (L2-resident)
//     instead of 112 scattered scalar loads + 112 f2bf + 14 divisions.
//   - tap LDS-geometry offsets are compile-time constants selected per qh via
//     cndmask (geo24() constexpr), killing the runtime /9 /3 chains.
//   - staging uses v_cvt_pk_bf16_f32 (HW RNE, 2 floats/instr) instead of the
//     4-op integer RNE sequence per value.
//   - __launch_bounds__(256,4): LDS 31232 B fits 5 blocks/CU, VGPRs ~68-90,
//     so 4 blocks/CU (16 waves) instead of 3 for latency hiding.
// Layout/geometry identical to round 2 (verified): block = 4x4x16 tile, halo
// 6x6x18 in LDS @ 48 B/voxel stride; wave = x-slice; 14x mfma_16x16x32_bf16
// per z-run (28th tap zero-weighted, A-addr clamped to tap 26).

#define NLEV 16
#define NTOT 1844282

typedef short  short8 __attribute__((ext_vector_type(8)));
typedef float  f32x4  __attribute__((ext_vector_type(4)));
typedef unsigned int u32x4 __attribute__((ext_vector_type(4)));

__constant__ int c_res[NLEV]  = {16,18,20,22,24,27,30,34,38,42,47,52,58,64,72,80};
__constant__ int c_voff[NLEV] = {0,4096,9928,17928,28576,42400,62083,89083,
                                 128387,183259,257347,361170,501778,696890,
                                 959034,1332282};
// tiles per level: ceil(R/4)^2 * ceil(R/16), cumulative
__constant__ int c_tblk[NLEV+1] = {0,16,66,116,188,260,358,486,729,1029,1392,
                                   1824,2500,3400,4424,6044,8044};
__constant__ int c_ntz[NLEV] = {1,2,2,2,2,2,2,3,3,3,3,4,4,4,5,5};
__constant__ int c_nty[NLEV] = {4,5,5,6,6,7,8,9,10,11,12,13,15,16,18,20};

__device__ __forceinline__ unsigned short f2bf(float f) {
    union { float f; unsigned int u; } v; v.f = f;
    unsigned int u = v.u;
    return (unsigned short)((u + 0x7FFFu + ((u >> 16) & 1u)) >> 16);
}

// HW packed f32->bf16 (RNE), verified mnemonic on gfx950.
__device__ __forceinline__ unsigned int cvt_pk_bf16(float lo, float hi) {
    unsigned int r;
    asm("v_cvt_pk_bf16_f32 %0, %1, %2" : "=v"(r) : "v"(lo), "v"(hi));
    return r;
}

// LDS byte-geometry (in shorts) of tap t, clamped to 26 for the padded tap.
constexpr int geo24(int t) {
    int ta = t > 26 ? 26 : t;
    int kd = ta / 9, rr = ta - kd * 9, kh = rr / 3, kw = rr - kh * 3;
    return ((kd * 6 + kh) * 18 + kw) * 24;
}

__device__ __forceinline__ short8 lds_load8(const short* p) {
    return *reinterpret_cast<const short8*>(__builtin_assume_aligned(p, 16));
}

// ---- one-shot: per-lane bf16 B-fragments -> wbuf[l][i][lane][8] (229,376 B) ----
__global__ void pack_weights(const float* __restrict__ w,
                             unsigned short* __restrict__ wbuf) {
    const int l = blockIdx.x;
    const float* wlev = w + l * 6912;                 // 27*16*16
    for (int task = threadIdx.x; task < 14 * 64; task += blockDim.x) {
        const int i    = task >> 6;                   // tap pair 0..13
        const int lane = task & 63;
        const int quad = lane >> 4;
        const int m    = lane & 15;                   // c_out
        const int h8   = (quad & 1) * 8;              // ci half
        const int qh   = quad >> 1;                   // tap parity
        const int t    = 2 * i + qh;                  // tap 0..27
        short8 v;
        if (t < 27) {
            const float* wp = wlev + t * 256 + h8 * 16 + m;
#pragma unroll
            for (int j = 0; j < 8; ++j) v[j] = (short)f2bf(wp[j * 16]);
        } else {
#pragma unroll
            for (int j = 0; j < 8; ++j) v[j] = 0;     // zero-weighted pad tap
        }
        *reinterpret_cast<short8*>(wbuf + l * 7168 + task * 8) = v;
    }
}

__global__ __launch_bounds__(256, 4)
void conv3d_mfma_kernel(const float* __restrict__ in,
                        const unsigned short* __restrict__ wbuf,
                        const float* __restrict__ bias,
                        float* __restrict__ out) {
    // 648 halo voxels * 24 shorts (16 data + 8 pad) = 31104 B
    __shared__ __align__(16) short s_in[648 * 24];

    const int bid = blockIdx.x;
    const int b   = blockIdx.y;

    int l = 0;
#pragma unroll
    for (int i = 1; i < NLEV; ++i) l += (bid >= c_tblk[i]);

    const int R    = c_res[l];
    const int voff = c_voff[l];
    const int ntz  = c_ntz[l];
    const int nty  = c_nty[l];

    const int local = bid - c_tblk[l];
    const int tz = local % ntz;
    const int t2 = local / ntz;
    const int ty = t2 % nty;
    const int tx = t2 / nty;

    const float* inb  = in  + ((long long)b * NTOT + voff) * 16;
    float*       outb = out + ((long long)b * NTOT + voff) * 16;

    // ---- stage halo tile (6 x 6 x 18) into LDS as bf16, zeros outside ----
    for (int h = threadIdx.x; h < 648; h += 256) {
        const int hz = h % 18;
        const int t  = h / 18;
        const int hy = t % 6;
        const int hx = t / 6;
        const int gx = tx * 4 - 1 + hx;
        const int gy = ty * 4 - 1 + hy;
        const int gz = tz * 16 - 1 + hz;
        const bool ok = ((unsigned)gx < (unsigned)R) &
                        ((unsigned)gy < (unsigned)R) &
                        ((unsigned)gz < (unsigned)R);
        u32x4 lo = {0u, 0u, 0u, 0u}, hi = {0u, 0u, 0u, 0u};
        if (ok) {
            const f32x4* ip = reinterpret_cast<const f32x4*>(
                inb + (long long)(((gx * R + gy) * R + gz) * 16));
            f32x4 q0 = ip[0], q1 = ip[1], q2 = ip[2], q3 = ip[3];
            lo[0] = cvt_pk_bf16(q0[0], q0[1]);
            lo[1] = cvt_pk_bf16(q0[2], q0[3]);
            lo[2] = cvt_pk_bf16(q1[0], q1[1]);
            lo[3] = cvt_pk_bf16(q1[2], q1[3]);
            hi[0] = cvt_pk_bf16(q2[0], q2[1]);
            hi[1] = cvt_pk_bf16(q2[2], q2[3]);
            hi[2] = cvt_pk_bf16(q3[0], q3[1]);
            hi[3] = cvt_pk_bf16(q3[2], q3[3]);
        }
        *reinterpret_cast<u32x4*>(&s_in[h * 24])     = lo;
        *reinterpret_cast<u32x4*>(&s_in[h * 24 + 8]) = hi;
    }

    // ---- per-lane geometry + prepacked weight fragments (in flight over barrier) ----
    const int lane = threadIdx.x & 63;
    const int wv   = threadIdx.x >> 6;     // wave id = dx
    const int quad = lane >> 4;
    const int m    = lane & 15;            // A-row (z) / D-col (c_out)
    const int co   = m;
    const int h8   = (quad & 1) * 8;       // ci half
    const int qh   = quad >> 1;            // tap parity

    const float bv = bias[l * 16 + co];

    // 14 coalesced 16 B loads per lane; level fragment block is 14.3 KB (L2-hit).
    short8 wf[14];
    const short8* wp8 = reinterpret_cast<const short8*>(wbuf) + l * 896 + lane;
#pragma unroll
    for (int i = 0; i < 14; ++i) wf[i] = wp8[i * 64];

    // LDS A-offsets: compile-time constants per (i,qh), + per-lane base.
    const int mbase = m * 24 + h8;
    int ofs[14];
#pragma unroll
    for (int i = 0; i < 14; ++i)
        ofs[i] = (qh ? geo24(2 * i + 1) : geo24(2 * i)) + mbase;

    __syncthreads();

    // ---- compute: wave = x-slice dx=wv; 4 z-runs (dy=0..3) of 16 voxels ----
    const int gx = tx * 4 + wv;
    if (gx < R) {
        const int pb0 = wv * 2592;          // (dx*6)*18*24
#pragma unroll
        for (int j = 0; j < 4; ++j) {
            const int gy = ty * 4 + j;
            if (gy < R) {
                f32x4 acc = {bv, bv, bv, bv};
                const int pb = pb0 + j * 432;   // + dy*18*24
#pragma unroll
                for (int i = 0; i < 14; ++i) {
                    short8 a = lds_load8(&s_in[pb + ofs[i]]);
                    acc = __builtin_amdgcn_mfma_f32_16x16x32_bf16(a, wf[i], acc, 0, 0, 0);
                }
                float* ob = outb + (long long)(gx * R + gy) * R * 16 + co;
                const int gz0 = tz * 16 + quad * 4;
#pragma unroll
                for (int r = 0; r < 4; ++r) {
                    const int gz = gz0 + r;
                    if (gz < R) ob[(long long)gz * 16] = acc[r];
                }
            }
        }
    }
}

extern "C" void kernel_launch(void* const* d_in, const int* in_sizes, int n_in,
                              void* d_out, int out_size, void* d_ws, size_t ws_size,
                              hipStream_t stream) {
    const float* in   = (const float*)d_in[0];   // (B, N, 16) fp32
    const float* w    = (const float*)d_in[1];   // (16, 3,3,3, 16, 16) fp32
    const float* bias = (const float*)d_in[2];   // (16, 16) fp32
    float* out = (float*)d_out;                  // (B, N, 16) fp32
    unsigned short* wbuf = (unsigned short*)d_ws; // uses 229,376 B of workspace

    pack_weights<<<dim3(NLEV), 256, 0, stream>>>(w, wbuf);
    dim3 grid(8044, 2);
    conv3d_mfma_kernel<<<grid, 256, 0, stream>>>(in, wbuf, bias, out);
}